// Round 1
// baseline (255.580 us; speedup 1.0000x reference)
//
#include <hip/hip_runtime.h>
#include <math.h>

// Problem constants
#define R_   1152
#define C_   10
#define D_   16
#define I_   8
#define B_   256
#define N_   160      // C_*D_ (n = c*16+d)
#define K_   9216     // R_*I_ (k = r*8+i)
#define KS_  32       // K-split across blocks
#define KC_  288      // K_/KS_ per block
#define KW_  72       // per-wave k slice (KC_/4)

// ---------------------------------------------------------------------------
// Wsum[r,c,i] = sum_d W[r,c,d,i]
__global__ void wsum_kernel(const float* __restrict__ W, float* __restrict__ Wsum) {
    int idx = blockIdx.x * 256 + threadIdx.x;      // 360 blocks -> 92160 exact
    int r = idx / (C_ * I_);
    int rem = idx % (C_ * I_);
    int c = rem / I_;
    int i = rem % I_;
    const float* p = W + (size_t)r * (C_ * D_ * I_) + c * (D_ * I_) + i;
    float s = 0.0f;
#pragma unroll
    for (int d = 0; d < D_; ++d) s += p[d * I_];
    Wsum[idx] = s;
}

// ---------------------------------------------------------------------------
// t[b,r,c] = sum_i Wsum[r,c,i] * u[b,r,i]
__global__ void t_kernel(const float* __restrict__ u, const float* __restrict__ Wsum,
                         float* __restrict__ t) {
    int idx = blockIdx.x * 256 + threadIdx.x;      // 1152 blocks -> 294912 = B_*R_ exact
    int r = idx % R_;
    const float4* up = (const float4*)(u + (size_t)idx * I_);
    float4 a0 = up[0], a1 = up[1];
    const float* wp = Wsum + (size_t)r * (C_ * I_);
    float out[C_];
#pragma unroll
    for (int c = 0; c < C_; ++c) {
        const float4* w4 = (const float4*)(wp + c * I_);
        float4 w0 = w4[0], w1 = w4[1];
        out[c] = a0.x * w0.x + a0.y * w0.y + a0.z * w0.z + a0.w * w0.w
               + a1.x * w1.x + a1.y * w1.y + a1.z * w1.z + a1.w * w1.w;
    }
    float* tp = t + (size_t)idx * C_;
#pragma unroll
    for (int c = 0; c < C_; ++c) tp[c] = out[c];
}

// ---------------------------------------------------------------------------
// WT[k][n] = W[r][n][i]   (k = r*8+i) — plain transpose for pass 0
__global__ void wt0_kernel(const float* __restrict__ W, float* __restrict__ WT) {
    int q = blockIdx.x * 256 + threadIdx.x;        // 1440 blocks -> 368640 = K_*N_/4 exact
    int k = q / (N_ / 4);
    int n4 = (q % (N_ / 4)) * 4;
    int r = k >> 3, i = k & 7;
    const float* wp = W + (size_t)r * (C_ * D_ * I_) + n4 * I_ + i;
    float4 o;
    o.x = wp[0]; o.y = wp[8]; o.z = wp[16]; o.w = wp[24];
    ((float4*)WT)[q] = o;
}

// ---------------------------------------------------------------------------
// WT[k][n] = W[r][n][i] * softmax_r(bij)[r][n]
__global__ void wtmod_kernel(const float* __restrict__ W, const float* __restrict__ bij,
                             const float* __restrict__ nmax, const float* __restrict__ nsum,
                             float* __restrict__ WT) {
    int q = blockIdx.x * 256 + threadIdx.x;        // 1440 blocks
    int k = q / (N_ / 4);
    int n4 = (q % (N_ / 4)) * 4;
    int r = k >> 3, i = k & 7;
    const float* wp = W + (size_t)r * (C_ * D_ * I_) + n4 * I_ + i;
    float4 bb = *(const float4*)(bij + (size_t)r * N_ + n4);
    float4 mm = *(const float4*)(nmax + n4);
    float4 ss = *(const float4*)(nsum + n4);
    float4 o;
    o.x = wp[0]  * (__expf(bb.x - mm.x) / ss.x);
    o.y = wp[8]  * (__expf(bb.y - mm.y) / ss.y);
    o.z = wp[16] * (__expf(bb.z - mm.z) / ss.z);
    o.w = wp[24] * (__expf(bb.w - mm.w) / ss.w);
    ((float4*)WT)[q] = o;
}

// ---------------------------------------------------------------------------
// partials[ks][b*160+n] = sum over k-slice of u[b][k]*WT[k][n]
// grid (KS_, 16 b-tiles), 256 threads. Wave w handles k in [x*288 + w*72, +72),
// lane tile 4b x 10n over a 16b x 160n block tile. Operands straight from
// global (L1/L2-resident); LDS only for cross-wave epilogue reduction.
__launch_bounds__(256)
__global__ void gemm_kernel(const float* __restrict__ u, const float* __restrict__ WT,
                            float* __restrict__ partials) {
    __shared__ float red[4 * 2560];
    int tid = threadIdx.x;
    int wave = tid >> 6, lane = tid & 63;
    int ng = lane & 15, bg = lane >> 4;
    int b0 = blockIdx.y * 16;
    int kbase = blockIdx.x * KC_ + wave * KW_;
    int n0 = ng * 10;

    float acc[4][10];
#pragma unroll
    for (int m = 0; m < 4; ++m)
#pragma unroll
        for (int j = 0; j < 10; ++j) acc[m][j] = 0.0f;

    const float* ur[4];
#pragma unroll
    for (int m = 0; m < 4; ++m) ur[m] = u + (size_t)(b0 + bg * 4 + m) * K_;

    for (int kk = 0; kk < KW_; kk += 4) {
        int k = kbase + kk;
        float ua[4][4];
#pragma unroll
        for (int m = 0; m < 4; ++m) {
            float4 tmp = *(const float4*)(ur[m] + k);
            ua[m][0] = tmp.x; ua[m][1] = tmp.y; ua[m][2] = tmp.z; ua[m][3] = tmp.w;
        }
#pragma unroll
        for (int t4 = 0; t4 < 4; ++t4) {
            const float* wrow = WT + (size_t)(k + t4) * N_ + n0;
            float w[10];
#pragma unroll
            for (int j = 0; j < 10; j += 2) {
                float2 ww = *(const float2*)(wrow + j);
                w[j] = ww.x; w[j + 1] = ww.y;
            }
#pragma unroll
            for (int m = 0; m < 4; ++m)
#pragma unroll
                for (int j = 0; j < 10; ++j)
                    acc[m][j] = fmaf(ua[m][t4], w[j], acc[m][j]);
        }
    }

    // epilogue: reduce the 4 waves' partial tiles in LDS, store coalesced
#pragma unroll
    for (int m = 0; m < 4; ++m)
#pragma unroll
        for (int j = 0; j < 10; ++j)
            red[wave * 2560 + (bg * 4 + m) * N_ + n0 + j] = acc[m][j];
    __syncthreads();
    float* outp = partials + (size_t)blockIdx.x * (B_ * N_) + (size_t)b0 * N_;
    for (int f = tid; f < 2560; f += 256)
        outp[f] = red[f] + red[2560 + f] + red[5120 + f] + red[7680 + f];
}

// ---------------------------------------------------------------------------
// s = scale * sum_ks partials; v = squash(s)
__global__ void reduce_squash_kernel(const float* __restrict__ partials,
                                     float* __restrict__ dst, float scale) {
    int g = blockIdx.x * 256 + threadIdx.x;        // 160 blocks -> 40960 exact
    float s = 0.0f;
#pragma unroll
    for (int ks = 0; ks < KS_; ++ks) s += partials[(size_t)ks * (B_ * N_) + g];
    s *= scale;
    float sq = s * s;
    dst[g] = sq / (1.0f + sq) * s / (sqrtf(sq) + 1e-5f);
}

// ---------------------------------------------------------------------------
// bij[r][n] (+)= (1/B) * sum_b v[b][n] * t[b][r][c(n)]
__global__ void bupdate_kernel(const float* __restrict__ v, const float* __restrict__ t,
                               float* __restrict__ bij, int accumulate) {
    int id = blockIdx.x * 256 + threadIdx.x;       // 180 blocks -> 46080 = 288*160 exact
    int rq = id / N_;                               // r-quad 0..287
    int n = id % N_;
    int c = n >> 4;
    float acc[4] = {0.0f, 0.0f, 0.0f, 0.0f};
    for (int b = 0; b < B_; ++b) {
        float vv = v[b * N_ + n];
        const float* tb = t + ((size_t)b * R_ + rq * 4) * C_ + c;
#pragma unroll
        for (int m = 0; m < 4; ++m) acc[m] = fmaf(vv, tb[m * C_], acc[m]);
    }
#pragma unroll
    for (int m = 0; m < 4; ++m) {
        float val = acc[m] * (1.0f / B_);
        int o = (rq * 4 + m) * N_ + n;
        bij[o] = accumulate ? (bij[o] + val) : val;
    }
}

// ---------------------------------------------------------------------------
// per-n softmax stats over r: nmax[n], nsum[n] = sum_r exp(b - nmax)
__global__ void colstat_kernel(const float* __restrict__ bij,
                               float* __restrict__ nmax, float* __restrict__ nsum) {
    int n = blockIdx.x;                             // 160 blocks
    int tid = threadIdx.x;                          // 256
    __shared__ float wred[4], wred2[4];
    float mx = -1e30f;
    for (int r = tid; r < R_; r += 256) mx = fmaxf(mx, bij[r * N_ + n]);
#pragma unroll
    for (int off = 32; off > 0; off >>= 1) mx = fmaxf(mx, __shfl_down(mx, off, 64));
    if ((tid & 63) == 0) wred[tid >> 6] = mx;
    __syncthreads();
    mx = fmaxf(fmaxf(wred[0], wred[1]), fmaxf(wred[2], wred[3]));
    float s = 0.0f;
    for (int r = tid; r < R_; r += 256) s += __expf(bij[r * N_ + n] - mx);
#pragma unroll
    for (int off = 32; off > 0; off >>= 1) s += __shfl_down(s, off, 64);
    if ((tid & 63) == 0) wred2[tid >> 6] = s;
    __syncthreads();
    if (tid == 0) {
        nmax[n] = mx;
        nsum[n] = wred2[0] + wred2[1] + wred2[2] + wred2[3];
    }
}

// ---------------------------------------------------------------------------
extern "C" void kernel_launch(void* const* d_in, const int* in_sizes, int n_in,
                              void* d_out, int out_size, void* d_ws, size_t ws_size,
                              hipStream_t stream) {
    (void)in_sizes; (void)n_in; (void)out_size; (void)ws_size;
    const float* u = (const float*)d_in[0];
    const float* W = (const float*)d_in[1];
    float* out = (float*)d_out;

    // workspace layout (floats); total 6,052,160 floats = 24.2 MB
    float* ws      = (float*)d_ws;
    float* WT      = ws;                    // 1,474,560
    float* Wsum    = WT + 1474560;          //    92,160
    float* t       = Wsum + 92160;          // 2,949,120
    float* v       = t + 2949120;           //    40,960
    float* bij     = v + 40960;             //   184,320  layout [r][n]
    float* nmax    = bij + 184320;          //       160
    float* nsum    = nmax + 160;            //       160
    float* partials= nsum + 160;            // 1,310,720 (KS_ * 40960)

    wsum_kernel<<<360, 256, 0, stream>>>(W, Wsum);
    t_kernel<<<1152, 256, 0, stream>>>(u, Wsum, t);
    wt0_kernel<<<1440, 256, 0, stream>>>(W, WT);

    for (int iter = 0; iter < 3; ++iter) {
        gemm_kernel<<<dim3(KS_, 16), 256, 0, stream>>>(u, WT, partials);
        reduce_squash_kernel<<<160, 256, 0, stream>>>(
            partials, (iter == 2) ? out : v, (iter == 0) ? (1.0f / 1152.0f) : 1.0f);
        if (iter < 2) {
            bupdate_kernel<<<180, 256, 0, stream>>>(v, t, bij, iter);
            colstat_kernel<<<160, 256, 0, stream>>>(bij, nmax, nsum);
            wtmod_kernel<<<1440, 256, 0, stream>>>(W, bij, nmax, nsum, WT);
        }
    }
}

// Round 2
// 215.595 us; speedup vs baseline: 1.1855x; 1.1855x over previous
//
#include <hip/hip_runtime.h>
#include <math.h>

// Problem constants
#define R_   1152
#define C_   10
#define D_   16
#define I_   8
#define B_   256
#define N_   160      // C_*D_ (n = c*16+d)
#define K_   9216     // R_*I_ (k = r*8+i)
#define KS_  32       // K-split across blocks
#define KC_  288      // K_/KS_ per block
#define KW_  72       // per-wave k slice (KC_/4)

// ---------------------------------------------------------------------------
// Fused setup: blocks [0,360): Wsum[r,c,i] = sum_d W[r,c,d,i]
//              blocks [360,1800): WT[k][n] = W[r][n][i]  (k = r*8+i)
__global__ void prep_kernel(const float* __restrict__ W, float* __restrict__ Wsum,
                            float* __restrict__ WT) {
    if (blockIdx.x < 360) {
        int idx = blockIdx.x * 256 + threadIdx.x;      // 92160 exact
        int r = idx / (C_ * I_);
        int rem = idx % (C_ * I_);
        int c = rem / I_;
        int i = rem % I_;
        const float* p = W + (size_t)r * (C_ * D_ * I_) + c * (D_ * I_) + i;
        float s = 0.0f;
#pragma unroll
        for (int d = 0; d < D_; ++d) s += p[d * I_];
        Wsum[idx] = s;
    } else {
        int q = (blockIdx.x - 360) * 256 + threadIdx.x; // 368640 = K_*N_/4 exact
        int k = q / (N_ / 4);
        int n4 = (q % (N_ / 4)) * 4;
        int r = k >> 3, i = k & 7;
        const float* wp = W + (size_t)r * (C_ * D_ * I_) + n4 * I_ + i;
        float4 o;
        o.x = wp[0]; o.y = wp[8]; o.z = wp[16]; o.w = wp[24];
        ((float4*)WT)[q] = o;
    }
}

// ---------------------------------------------------------------------------
// tT[c][b][r] = sum_i Wsum[r,c,i] * u[b,r,i]   (layout chosen for bupdate reads)
__global__ void t_kernel(const float* __restrict__ u, const float* __restrict__ Wsum,
                         float* __restrict__ tT) {
    int idx = blockIdx.x * 256 + threadIdx.x;      // 1152 blocks -> 294912 = B_*R_ exact
    int r = idx % R_;
    int b = idx / R_;
    const float4* up = (const float4*)(u + (size_t)idx * I_);
    float4 a0 = up[0], a1 = up[1];
    const float* wp = Wsum + (size_t)r * (C_ * I_);
    float out[C_];
#pragma unroll
    for (int c = 0; c < C_; ++c) {
        const float4* w4 = (const float4*)(wp + c * I_);
        float4 w0 = w4[0], w1 = w4[1];
        out[c] = a0.x * w0.x + a0.y * w0.y + a0.z * w0.z + a0.w * w0.w
               + a1.x * w1.x + a1.y * w1.y + a1.z * w1.z + a1.w * w1.w;
    }
#pragma unroll
    for (int c = 0; c < C_; ++c)
        tT[((size_t)c * B_ + b) * R_ + r] = out[c];   // coalesced across lanes (r)
}

// ---------------------------------------------------------------------------
// WT[k][n] = W[r][n][i] * softmax_r(bij)[r][n]
__global__ void wtmod_kernel(const float* __restrict__ W, const float* __restrict__ bij,
                             const float* __restrict__ nmax, const float* __restrict__ nsum,
                             float* __restrict__ WT) {
    int q = blockIdx.x * 256 + threadIdx.x;        // 1440 blocks
    int k = q / (N_ / 4);
    int n4 = (q % (N_ / 4)) * 4;
    int r = k >> 3, i = k & 7;
    const float* wp = W + (size_t)r * (C_ * D_ * I_) + n4 * I_ + i;
    float4 bb = *(const float4*)(bij + (size_t)r * N_ + n4);
    float4 mm = *(const float4*)(nmax + n4);
    float4 ss = *(const float4*)(nsum + n4);
    float4 o;
    o.x = wp[0]  * (__expf(bb.x - mm.x) / ss.x);
    o.y = wp[8]  * (__expf(bb.y - mm.y) / ss.y);
    o.z = wp[16] * (__expf(bb.z - mm.z) / ss.z);
    o.w = wp[24] * (__expf(bb.w - mm.w) / ss.w);
    ((float4*)WT)[q] = o;
}

// ---------------------------------------------------------------------------
// partials[ks][b*160+n] = sum over k-slice of u[b][k]*WT[k][n]
__launch_bounds__(256)
__global__ void gemm_kernel(const float* __restrict__ u, const float* __restrict__ WT,
                            float* __restrict__ partials) {
    __shared__ float red[4 * 2560];
    int tid = threadIdx.x;
    int wave = tid >> 6, lane = tid & 63;
    int ng = lane & 15, bg = lane >> 4;
    int b0 = blockIdx.y * 16;
    int kbase = blockIdx.x * KC_ + wave * KW_;
    int n0 = ng * 10;

    float acc[4][10];
#pragma unroll
    for (int m = 0; m < 4; ++m)
#pragma unroll
        for (int j = 0; j < 10; ++j) acc[m][j] = 0.0f;

    const float* ur[4];
#pragma unroll
    for (int m = 0; m < 4; ++m) ur[m] = u + (size_t)(b0 + bg * 4 + m) * K_;

    for (int kk = 0; kk < KW_; kk += 4) {
        int k = kbase + kk;
        float ua[4][4];
#pragma unroll
        for (int m = 0; m < 4; ++m) {
            float4 tmp = *(const float4*)(ur[m] + k);
            ua[m][0] = tmp.x; ua[m][1] = tmp.y; ua[m][2] = tmp.z; ua[m][3] = tmp.w;
        }
#pragma unroll
        for (int t4 = 0; t4 < 4; ++t4) {
            const float* wrow = WT + (size_t)(k + t4) * N_ + n0;
            float w[10];
#pragma unroll
            for (int j = 0; j < 10; j += 2) {
                float2 ww = *(const float2*)(wrow + j);
                w[j] = ww.x; w[j + 1] = ww.y;
            }
#pragma unroll
            for (int m = 0; m < 4; ++m)
#pragma unroll
                for (int j = 0; j < 10; ++j)
                    acc[m][j] = fmaf(ua[m][t4], w[j], acc[m][j]);
        }
    }

#pragma unroll
    for (int m = 0; m < 4; ++m)
#pragma unroll
        for (int j = 0; j < 10; ++j)
            red[wave * 2560 + (bg * 4 + m) * N_ + n0 + j] = acc[m][j];
    __syncthreads();
    float* outp = partials + (size_t)blockIdx.x * (B_ * N_) + (size_t)b0 * N_;
    for (int f = tid; f < 2560; f += 256)
        outp[f] = red[f] + red[2560 + f] + red[5120 + f] + red[7680 + f];
}

// ---------------------------------------------------------------------------
// s = scale * sum_ks partials; v = squash(s)
__global__ void reduce_squash_kernel(const float* __restrict__ partials,
                                     float* __restrict__ dst, float scale) {
    int g = blockIdx.x * 256 + threadIdx.x;        // 160 blocks -> 40960 exact
    float s = 0.0f;
#pragma unroll
    for (int ks = 0; ks < KS_; ++ks) s += partials[(size_t)ks * (B_ * N_) + g];
    s *= scale;
    float sq = s * s;
    dst[g] = sq / (1.0f + sq) * s / (sqrtf(sq) + 1e-5f);
}

// ---------------------------------------------------------------------------
// bij[r][n] (+)= (1/B) * sum_b v[b][n] * tT[c][b][r]
// grid (18, 10): 64 r-lanes x 4 b-slices per block; v staged in LDS.
__launch_bounds__(256)
__global__ void bupdate_kernel(const float* __restrict__ v, const float* __restrict__ tT,
                               float* __restrict__ bij, int accumulate) {
    __shared__ float vs[B_ * 16];     // 16 KB, [b][d]
    __shared__ float red[16 * 256];   // 16 KB, [d][tid]
    int tid = threadIdx.x;
    int c = blockIdx.y;
    int r0 = blockIdx.x * 64;
    int rsub = tid & 63, bs = tid >> 6;

    // stage v[:, c*16 .. c*16+16) -> vs  (1024 float4 loads)
    for (int q = tid; q < 1024; q += 256) {
        int b = q >> 2, d4 = q & 3;
        ((float4*)vs)[q] = *(const float4*)(v + (size_t)b * N_ + c * 16 + d4 * 4);
    }
    __syncthreads();

    float acc[16];
#pragma unroll
    for (int d = 0; d < 16; ++d) acc[d] = 0.0f;

    const float* tp = tT + ((size_t)c * B_ + bs * 64) * R_ + r0 + rsub;
    for (int bb = 0; bb < 64; ++bb) {
        float tv = tp[(size_t)bb * R_];                   // coalesced across wave
        const float4* vrow = (const float4*)(vs + (bs * 64 + bb) * 16); // wave-uniform
        float4 v0 = vrow[0], v1 = vrow[1], v2 = vrow[2], v3 = vrow[3];
        acc[0]  = fmaf(tv, v0.x, acc[0]);  acc[1]  = fmaf(tv, v0.y, acc[1]);
        acc[2]  = fmaf(tv, v0.z, acc[2]);  acc[3]  = fmaf(tv, v0.w, acc[3]);
        acc[4]  = fmaf(tv, v1.x, acc[4]);  acc[5]  = fmaf(tv, v1.y, acc[5]);
        acc[6]  = fmaf(tv, v1.z, acc[6]);  acc[7]  = fmaf(tv, v1.w, acc[7]);
        acc[8]  = fmaf(tv, v2.x, acc[8]);  acc[9]  = fmaf(tv, v2.y, acc[9]);
        acc[10] = fmaf(tv, v2.z, acc[10]); acc[11] = fmaf(tv, v2.w, acc[11]);
        acc[12] = fmaf(tv, v3.x, acc[12]); acc[13] = fmaf(tv, v3.y, acc[13]);
        acc[14] = fmaf(tv, v3.z, acc[14]); acc[15] = fmaf(tv, v3.w, acc[15]);
    }
#pragma unroll
    for (int d = 0; d < 16; ++d) red[d * 256 + tid] = acc[d];  // conflict-free
    __syncthreads();

    for (int q = tid; q < 1024; q += 256) {
        int rr = q & 63, d = q >> 6;
        const float* rp = red + d * 256 + rr;
        float s = (rp[0] + rp[64] + rp[128] + rp[192]) * (1.0f / B_);
        int o = (r0 + rr) * N_ + c * 16 + d;
        bij[o] = accumulate ? (bij[o] + s) : s;
    }
}

// ---------------------------------------------------------------------------
// per-n softmax stats over r: nmax[n], nsum[n] = sum_r exp(b - nmax)
__global__ void colstat_kernel(const float* __restrict__ bij,
                               float* __restrict__ nmax, float* __restrict__ nsum) {
    int n = blockIdx.x;                             // 160 blocks
    int tid = threadIdx.x;                          // 256
    __shared__ float wred[4], wred2[4];
    float mx = -1e30f;
    for (int r = tid; r < R_; r += 256) mx = fmaxf(mx, bij[r * N_ + n]);
#pragma unroll
    for (int off = 32; off > 0; off >>= 1) mx = fmaxf(mx, __shfl_down(mx, off, 64));
    if ((tid & 63) == 0) wred[tid >> 6] = mx;
    __syncthreads();
    mx = fmaxf(fmaxf(wred[0], wred[1]), fmaxf(wred[2], wred[3]));
    float s = 0.0f;
    for (int r = tid; r < R_; r += 256) s += __expf(bij[r * N_ + n] - mx);
#pragma unroll
    for (int off = 32; off > 0; off >>= 1) s += __shfl_down(s, off, 64);
    if ((tid & 63) == 0) wred2[tid >> 6] = s;
    __syncthreads();
    if (tid == 0) {
        nmax[n] = mx;
        nsum[n] = wred2[0] + wred2[1] + wred2[2] + wred2[3];
    }
}

// ---------------------------------------------------------------------------
extern "C" void kernel_launch(void* const* d_in, const int* in_sizes, int n_in,
                              void* d_out, int out_size, void* d_ws, size_t ws_size,
                              hipStream_t stream) {
    (void)in_sizes; (void)n_in; (void)out_size; (void)ws_size;
    const float* u = (const float*)d_in[0];
    const float* W = (const float*)d_in[1];
    float* out = (float*)d_out;

    // workspace layout (floats); total ~24.2 MB
    float* ws      = (float*)d_ws;
    float* WT      = ws;                    // 1,474,560
    float* Wsum    = WT + 1474560;          //    92,160
    float* tT      = Wsum + 92160;          // 2,949,120  layout [c][b][r]
    float* v       = tT + 2949120;          //    40,960
    float* bij     = v + 40960;             //   184,320  layout [r][n]
    float* nmax    = bij + 184320;          //       160
    float* nsum    = nmax + 160;            //       160
    float* partials= nsum + 160;            // 1,310,720 (KS_ * 40960)

    prep_kernel<<<1800, 256, 0, stream>>>(W, Wsum, WT);
    t_kernel<<<1152, 256, 0, stream>>>(u, Wsum, tT);

    for (int iter = 0; iter < 3; ++iter) {
        gemm_kernel<<<dim3(KS_, 16), 256, 0, stream>>>(u, WT, partials);
        reduce_squash_kernel<<<160, 256, 0, stream>>>(
            partials, (iter == 2) ? out : v, (iter == 0) ? (1.0f / 1152.0f) : 1.0f);
        if (iter < 2) {
            bupdate_kernel<<<dim3(18, 10), 256, 0, stream>>>(v, tT, bij, iter);
            colstat_kernel<<<160, 256, 0, stream>>>(bij, nmax, nsum);
            wtmod_kernel<<<1440, 256, 0, stream>>>(W, bij, nmax, nsum, WT);
        }
    }
}